// Round 8
// baseline (181.307 us; speedup 1.0000x reference)
//
#include <hip/hip_runtime.h>

// Cholesky-from-partial-correlations.
//   out[b,i,j] = z_j * sqrt( prod_{k<j} (1 - z_k^2) )  for j < i;  1 on diag; 0 above.
// One wave per FOUR consecutive rows, loads hoisted as dwordx4 (R4 retry
// without its scalar-load confound): 4 vector loads up front, then 4
// independent DPP-scan+emit+store passes. Amortizes per-wave fixed cost
// (dispatch/setup/drain) 4x while keeping R7's VMEM efficiency.

#define SIZE 256
#define BATCH 512
#define M (SIZE * (SIZE - 1) / 2)   // 32640
#define TOTAL (BATCH * M)           // 16711680

typedef float f4u __attribute__((ext_vector_type(4), aligned(4)));

// p *= dpp_shifted(p); invalid lanes contribute 1.0f (identity) via `old`
template <int CTRL, int ROW_MASK>
__device__ __forceinline__ float scan_mul(float p) {
    int sh = __builtin_amdgcn_update_dpp(
        __builtin_bit_cast(int, 1.0f),
        __builtin_bit_cast(int, p),
        CTRL, ROW_MASK, 0xF, false);
    return p * __builtin_bit_cast(float, sh);
}

// whole-wave shift right by 1; lane 0 gets 1.0f (exclusive-scan carry-in)
__device__ __forceinline__ float excl_shift_one(float p) {
    int r = __builtin_amdgcn_update_dpp(
        __builtin_bit_cast(int, 1.0f),
        __builtin_bit_cast(int, p),
        0x138 /* wave_shr:1 */, 0xF, 0xF, false);
    return __builtin_bit_cast(float, r);
}

__global__ __launch_bounds__(256) void chol_from_z_kernel(
    const float* __restrict__ vec, float* __restrict__ out) {
    const int lane = threadIdx.x & 63;
    const int wib = __builtin_amdgcn_readfirstlane((int)threadIdx.x >> 6);
    const int wave = (int)blockIdx.x * 4 + wib;   // 0 .. 32767
    const int b  = wave >> 6;                     // batch (512)
    const int i0 = (wave & 63) << 2;              // first of 4 consecutive rows
    const int j0 = lane << 2;

    // ---- hoist all 4 row loads (vector, overlapped in flight) ----
    f4u zv[4];
    #pragma unroll
    for (int r = 0; r < 4; ++r) {
        const int i = i0 + r;
        const int row_off = b * M + ((i * (i - 1)) >> 1);
        const float* __restrict__ s = vec + row_off;
        const int maxidx = (TOTAL - 1) - row_off;
        if (j0 + 3 <= maxidx) {                   // false only for lane 63 of the
            zv[r] = *(const f4u*)(s + j0);        // globally-last row
        } else {
            zv[r].x = s[j0]; zv[r].y = s[j0 + 1]; zv[r].z = s[j0 + 2]; zv[r].w = 0.f;
        }
    }

    float* __restrict__ dst0 = out + (((size_t)b << 8) + (size_t)i0) * SIZE + j0;

    #pragma unroll
    for (int r = 0; r < 4; ++r) {
        const int i = i0 + r;
        const float z0 = (j0     < i) ? zv[r].x : 0.f;
        const float z1 = (j0 + 1 < i) ? zv[r].y : 0.f;
        const float z2 = (j0 + 2 < i) ? zv[r].z : 0.f;
        const float z3 = (j0 + 3 < i) ? zv[r].w : 0.f;

        const float t0 = 1.f - z0 * z0;
        const float t1 = 1.f - z1 * z1;
        const float t2 = 1.f - z2 * z2;
        const float t3 = 1.f - z3 * z3;

        float p = (t0 * t1) * (t2 * t3);
        p = scan_mul<0x111, 0xF>(p);              // row_shr:1
        p = scan_mul<0x112, 0xF>(p);              // row_shr:2
        p = scan_mul<0x114, 0xF>(p);              // row_shr:4
        p = scan_mul<0x118, 0xF>(p);              // row_shr:8
        if (i >= 64)  p = scan_mul<0x142, 0xA>(p);  // row_bcast:15
        if (i >= 128) p = scan_mul<0x143, 0xC>(p);  // row_bcast:31

        float run = excl_shift_one(p);

        f4u o;
        o.x = (j0     == i) ? 1.f : z0 * __builtin_amdgcn_sqrtf(run); run *= t0;
        o.y = (j0 + 1 == i) ? 1.f : z1 * __builtin_amdgcn_sqrtf(run); run *= t1;
        o.z = (j0 + 2 == i) ? 1.f : z2 * __builtin_amdgcn_sqrtf(run); run *= t2;
        o.w = (j0 + 3 == i) ? 1.f : z3 * __builtin_amdgcn_sqrtf(run);

        *(f4u*)(dst0 + (size_t)r * SIZE) = o;     // 4 KiB contiguous per wave
    }
}

extern "C" void kernel_launch(void* const* d_in, const int* in_sizes, int n_in,
                              void* d_out, int out_size, void* d_ws, size_t ws_size,
                              hipStream_t stream) {
    const float* vec = (const float*)d_in[0];
    float* out = (float*)d_out;
    const int n_waves = BATCH * SIZE / 4;       // 32768 waves, 4 rows each
    const int blocks = n_waves / 4;             // 8192 blocks of 256 threads
    chol_from_z_kernel<<<blocks, 256, 0, stream>>>(vec, out);
}